// Round 10
// baseline (213.178 us; speedup 1.0000x reference)
//
#include <hip/hip_runtime.h>
#include <hip/hip_bf16.h>

typedef __hip_bfloat16 bf16;
typedef _Float16 f16;
typedef __attribute__((ext_vector_type(8))) __bf16 bf16x8;
typedef __attribute__((ext_vector_type(8))) _Float16 f16x8;
typedef __attribute__((ext_vector_type(4))) _Float16 f16x4;
typedef __attribute__((ext_vector_type(4))) float floatx4;

#define T_SEQ 2048
#define EMB   1024
#define LAMBDA_INIT 0.35550906759096926f

// round-to-nearest-even fp32 -> bf16
__device__ __forceinline__ bf16 f2bf(float f) {
  unsigned u;
  __builtin_memcpy(&u, &f, 4);
  u += 0x7FFF + ((u >> 16) & 1);
  unsigned short h = (unsigned short)(u >> 16);
  bf16 r;
  __builtin_memcpy(&r, &h, 2);
  return r;
}

__device__ __forceinline__ void gl_lds16(const void* g, void* l) {
  __builtin_amdgcn_global_load_lds((const __attribute__((address_space(1))) void*)g,
                                   (__attribute__((address_space(3))) void*)l, 16, 0, 0);
}

__device__ __forceinline__ floatx4 mfma_bf(bf16x8 a, bf16x8 b, floatx4 c) {
  return __builtin_amdgcn_mfma_f32_16x16x32_bf16(a, b, c, 0, 0, 0);
}
__device__ __forceinline__ floatx4 mfma_h(f16x8 a, f16x8 b, floatx4 c) {
  return __builtin_amdgcn_mfma_f32_16x16x32_f16(a, b, c, 0, 0, 0);
}

// =====================================================================
// fp32 -> fp16 conversion for x, Wq, Wk, Wv, Wo.
// =====================================================================
__global__ __launch_bounds__(256) void convert_kernel(
    const float* __restrict__ x,  const float* __restrict__ wq,
    const float* __restrict__ wk, const float* __restrict__ wv,
    const float* __restrict__ wo,
    f16* __restrict__ xf, f16* __restrict__ wqf, f16* __restrict__ wkf,
    f16* __restrict__ wvf, f16* __restrict__ wof)
{
  int b = blockIdx.x;
  const float* src; f16* dst; long off;
  if      (b < 2048) { src = x;  dst = xf;  off = (long)b * 1024; }
  else if (b < 3072) { src = wq; dst = wqf; off = (long)(b - 2048) * 1024; }
  else if (b < 4096) { src = wk; dst = wkf; off = (long)(b - 3072) * 1024; }
  else if (b < 5120) { src = wv; dst = wvf; off = (long)(b - 4096) * 1024; }
  else               { src = wo; dst = wof; off = (long)(b - 5120) * 1024; }
  long i = off + threadIdx.x * 4;
  float4 v = *(const float4*)(src + i);
  f16x4 o;
  o.x = (f16)v.x; o.y = (f16)v.y; o.z = (f16)v.z; o.w = (f16)v.w;
  *(f16x4*)(dst + i) = o;
}

// =====================================================================
// fp16 NT GEMM, 64x128 tile, BK=64, 24KB LDS staging.
// MODE 2 = RoPE-Q epilogue (fold 0.125) -> fp16; MODE 3 = RoPE-K (inv scale)
// MODE 0 = bf16 out (V);  MODE 1 = fp32 out (output projection)
// =====================================================================
template <int MODE>
__device__ __forceinline__ void gemm64x128_f16(
    const f16* __restrict__ A_, const f16* __restrict__ B_,
    void* C0v, int K, int ldc, int m0, int n0, char* smem)
{
  f16* As = (f16*)smem;              // 64 x 64 swz (8 KB)
  f16* Bs = (f16*)(smem + 8192);     // 128 x 64 swz (16 KB)
  const int tid  = threadIdx.x;
  const int wave = tid >> 6, lane = tid & 63, quad = lane >> 4, l16 = lane & 15;
  const int mo = (wave & 1) << 5;
  const int no = (wave >> 1) << 6;

  floatx4 acc[2][4];
  #pragma unroll
  for (int i = 0; i < 2; i++)
    #pragma unroll
    for (int j = 0; j < 4; j++) { acc[i][j][0]=0.f; acc[i][j][1]=0.f; acc[i][j][2]=0.f; acc[i][j][3]=0.f; }

  const int srow = tid >> 3;
  const int ch   = (tid & 7) ^ (srow & 7);
  const long aoff = (long)(m0 + srow) * K + ch * 8;
  const long boff = (long)(n0 + srow) * K + ch * 8;
  const int wb = wave << 10;

  for (int k0 = 0; k0 < K; k0 += 64) {
    #pragma unroll
    for (int rr = 0; rr < 2; rr++)
      gl_lds16(A_ + aoff + k0 + (long)rr * 32 * K, smem + wb + rr * 4096);
    #pragma unroll
    for (int rr = 0; rr < 4; rr++)
      gl_lds16(B_ + boff + k0 + (long)rr * 32 * K, smem + 8192 + wb + rr * 4096);
    __syncthreads();
    #pragma unroll
    for (int kt = 0; kt < 2; kt++) {
      f16x8 a[2], b[4];
      #pragma unroll
      for (int i = 0; i < 2; i++) {
        int m = mo + i * 16 + l16;
        a[i] = *(const f16x8*)(As + m * 64 + ((((kt << 2) | quad) ^ (m & 7)) << 3));
      }
      #pragma unroll
      for (int j = 0; j < 4; j++) {
        int n = no + j * 16 + l16;
        b[j] = *(const f16x8*)(Bs + n * 64 + ((((kt << 2) | quad) ^ (n & 7)) << 3));
      }
      #pragma unroll
      for (int i = 0; i < 2; i++)
        #pragma unroll
        for (int j = 0; j < 4; j++)
          acc[i][j] = mfma_h(a[i], b[j], acc[i][j]);
    }
    __syncthreads();
  }

  if (MODE == 1) {
    #pragma unroll
    for (int i = 0; i < 2; i++)
      #pragma unroll
      for (int j = 0; j < 4; j++)
        #pragma unroll
        for (int r = 0; r < 4; r++) {
          int row = m0 + mo + i * 16 + quad * 4 + r;
          int col = n0 + no + j * 16 + l16;
          ((float*)C0v)[(long)row * ldc + col] = acc[i][j][r];
        }
  } else {
    unsigned short* E = (unsigned short*)smem;   // 64x128 2-byte = 16 KB
    #pragma unroll
    for (int i = 0; i < 2; i++)
      #pragma unroll
      for (int j = 0; j < 4; j++)
        #pragma unroll
        for (int r = 0; r < 4; r++) {
          int row = mo + i * 16 + quad * 4 + r;
          int col = no + j * 16 + l16;
          float v = acc[i][j][r];
          unsigned short bits;
          if (MODE == 0) {
            bf16 t = f2bf(v);
            __builtin_memcpy(&bits, &t, 2);
          } else {
            float p = __shfl_xor(v, 1, 64);
            int d = col & 63;
            float fr = (float)(m0 + row) * __expf((float)(d >> 1) * -0.28782313662425574f);
            float sn, cs;
            sincosf(fr, &sn, &cs);
            float rot = (col & 1) ? fmaf(v, cs, p * sn) : fmaf(v, cs, -p * sn);
            float power = (float)(m0 + row - 1024) * (1.0f / 512.0f);
            if (MODE == 3) power = -power;
            float sv = fmaf(2.0f, (float)(d & 31), 25.6f) * (1.0f / 89.6f);
            float s = __expf(power * __logf(sv));
            float ov = rot * s;
            if (MODE == 2) ov *= 0.125f;
            f16 t = (f16)ov;
            __builtin_memcpy(&bits, &t, 2);
          }
          E[row * 128 + col] = bits;
        }
    __syncthreads();
    const int rr0 = tid >> 4;
    const int c8  = (tid & 15) * 8;
    #pragma unroll
    for (int p2 = 0; p2 < 4; p2++) {
      int row = p2 * 16 + rr0;
      *(uint4*)((unsigned short*)C0v + (long)(m0 + row) * ldc + n0 + c8) =
          *(const uint4*)(E + row * 128 + c8);
    }
  }
}

__global__ __launch_bounds__(256) void qkv_gemm(
    const f16* __restrict__ xf,
    const f16* __restrict__ wqf, const f16* __restrict__ wkf,
    const f16* __restrict__ wvf,
    f16* __restrict__ qf, f16* __restrict__ kf, bf16* __restrict__ vt)
{
  __shared__ char smem[24576];
  int bid = blockIdx.x;
  if (bid < 256) {
    gemm64x128_f16<2>(xf, wqf, qf, 1024, 1024, (bid >> 3) * 64, (bid & 7) * 128, smem);
  } else if (bid < 512) {
    bid -= 256;
    gemm64x128_f16<3>(xf, wkf, kf, 1024, 1024, (bid >> 3) * 64, (bid & 7) * 128, smem);
  } else {
    bid -= 512;
    gemm64x128_f16<0>(wvf, xf, vt, 1024, 2048, (bid >> 4) * 64, (bid & 15) * 128, smem);
  }
}

__global__ __launch_bounds__(256) void out_gemm(const f16* __restrict__ attn,
                                                const f16* __restrict__ Wo,
                                                float* __restrict__ out)
{
  __shared__ char smem[24576];
  gemm64x128_f16<1>(attn, Wo, out, 1024, 1024,
                    (blockIdx.x >> 3) * 64, (blockIdx.x & 7) * 128, smem);
}

// =====================================================================
// Differential flash attention, K-split partial pass, 64 q-rows/block.
// Grid 512: h = b>>6 (head pair), ks = (b>>5)&1 (K half), qb = b&31.
// Each wave handles 2 row-tiles (Q in registers — staging unchanged),
// so 48 MFMA per barrier pair instead of 16.
// Emits locally-normalized O (f16, coalesced) + local denominators.
// =====================================================================
__global__ __launch_bounds__(256) void diff_attn(
    const f16* __restrict__ qf_, const f16* __restrict__ kf_,
    const bf16* __restrict__ vt,
    f16* __restrict__ opart, float* __restrict__ lpart)
{
  __shared__ char smem[49152];
  // K0 @0 (8KB) | K1 @8192 (8KB) | V @16384 (16KB) | P @32768 (16KB)
  bf16* Vs = (bf16*)(smem + 16384);

  const int tid  = threadIdx.x;
  const int wave = tid >> 6, lane = tid & 63, quad = lane >> 4, l16 = lane & 15;
  const int h  = blockIdx.x >> 6;        // head pair 0..7
  const int ks = (blockIdx.x >> 5) & 1;  // K half
  const int qb = blockIdx.x & 31;        // q block 0..31 (64 rows each)
  const int hl = wave >> 1;
  const int rg = wave & 1;
  const int hh = h * 2 + hl;
  const int t0 = qb * 64 + rg * 16;      // row-tile rt adds +32*rt

  f16x8 qfr[2][2];
  #pragma unroll
  for (int rt = 0; rt < 2; rt++) {
    const f16* qrow = qf_ + (long)(t0 + rt * 32 + l16) * EMB + hh * 64;
    qfr[rt][0] = *(const f16x8*)(qrow + quad * 8);
    qfr[rt][1] = *(const f16x8*)(qrow + 32 + quad * 8);
  }

  floatx4 o[2][8];
  #pragma unroll
  for (int rt = 0; rt < 2; rt++)
    #pragma unroll
    for (int i = 0; i < 8; i++) { o[rt][i][0]=0.f; o[rt][i][1]=0.f; o[rt][i][2]=0.f; o[rt][i][3]=0.f; }
  float lr[2][4] = {{0.f,0.f,0.f,0.f},{0.f,0.f,0.f,0.f}};

  const int srow = lane >> 3;
  const int ch   = (lane & 7) ^ srow;
  const f16*  kgp = kf_ + (long)(h * 2 + (wave & 1)) * 64 + (long)srow * EMB + ch * 8;
  const bf16* vgp = vt + (long)(h * 128 + (wave - 2) * 64 + srow) * T_SEQ + ch * 8;
  char* ldstK = smem + wave * 8192;
  char* ldstV = smem + 16384 + (wave - 2) * 8192;

  const int kb0 = ks * 1024;
  for (int ki = 0; ki < 16; ki++) {
    const int kb = kb0 + ki * 64;
    if (wave < 2) {
      #pragma unroll
      for (int j = 0; j < 8; j++)
        gl_lds16(kgp + (long)kb * EMB + (long)j * 8 * EMB, ldstK + j * 1024);
    } else {
      #pragma unroll
      for (int j = 0; j < 8; j++)
        gl_lds16(vgp + kb + (long)j * 8 * T_SEQ, ldstV + j * 1024);
    }
    __syncthreads();

    const f16* Ks = (const f16*)(smem + hl * 8192);
    bf16* Pw = (bf16*)(smem + 32768) + wave * 2048;
    #pragma unroll
    for (int rt = 0; rt < 2; rt++) {
      floatx4 s4[4];
      #pragma unroll
      for (int nt = 0; nt < 4; nt++) {
        s4[nt][0]=0.f; s4[nt][1]=0.f; s4[nt][2]=0.f; s4[nt][3]=0.f;
        #pragma unroll
        for (int kt = 0; kt < 2; kt++) {
          int n = nt * 16 + l16;
          f16x8 kfr = *(const f16x8*)(Ks + n * 64 + ((((kt << 2) | quad) ^ (n & 7)) << 3));
          s4[nt] = mfma_h(qfr[rt][kt], kfr, s4[nt]);
        }
      }
      // static-offset softmax: P = exp2(s*log2e - 12*log2e)
      #pragma unroll
      for (int nt = 0; nt < 4; nt++)
        #pragma unroll
        for (int r = 0; r < 4; r++) {
          float pv = __builtin_amdgcn_exp2f(
              fmaf(s4[nt][r], 1.4426950408889634f, -17.312340490667562f));
          s4[nt][r] = pv;
          lr[rt][r] += pv;
        }
      // P (C-layout) -> LDS (swizzled)
      #pragma unroll
      for (int nt = 0; nt < 4; nt++) {
        int col = nt * 16 + l16;
        #pragma unroll
        for (int r = 0; r < 4; r++) {
          int row = quad * 4 + r;
          Pw[rt * 1024 + row * 64 + (((col >> 3) ^ (row & 7)) << 3) + (col & 7)] =
              f2bf(s4[nt][r]);
        }
      }
    }
    __asm__ volatile("s_waitcnt lgkmcnt(0)" ::: "memory");
    #pragma unroll
    for (int rt = 0; rt < 2; rt++) {
      bf16x8 pf[2];
      #pragma unroll
      for (int kt = 0; kt < 2; kt++)
        pf[kt] = *(const bf16x8*)(Pw + rt * 1024 + l16 * 64 +
                                  ((((kt << 2) | quad) ^ (l16 & 7)) << 3));
      #pragma unroll
      for (int nt = 0; nt < 8; nt++) {
        #pragma unroll
        for (int kt = 0; kt < 2; kt++) {
          int c = nt * 16 + l16;
          bf16x8 vf = *(const bf16x8*)(Vs + c * 64 + ((((kt << 2) | quad) ^ (c & 7)) << 3));
          o[rt][nt] = mfma_bf(pf[kt], vf, o[rt][nt]);
        }
      }
    }
    __syncthreads();
  }

  // local denominator reduction + local normalize
  #pragma unroll
  for (int rt = 0; rt < 2; rt++)
    #pragma unroll
    for (int r = 0; r < 4; r++) {
      lr[rt][r] += __shfl_xor(lr[rt][r], 1, 64);
      lr[rt][r] += __shfl_xor(lr[rt][r], 2, 64);
      lr[rt][r] += __shfl_xor(lr[rt][r], 4, 64);
      lr[rt][r] += __shfl_xor(lr[rt][r], 8, 64);
    }
  #pragma unroll
  for (int rt = 0; rt < 2; rt++)
    #pragma unroll
    for (int nt = 0; nt < 8; nt++)
      #pragma unroll
      for (int r = 0; r < 4; r++) o[rt][nt][r] /= lr[rt][r];

  // O -> LDS (2 heads x 64 rows x 128 f16 = 32KB) -> coalesced partial store
  f16* E = (f16*)smem;
  #pragma unroll
  for (int rt = 0; rt < 2; rt++)
    #pragma unroll
    for (int nt = 0; nt < 8; nt++)
      #pragma unroll
      for (int r = 0; r < 4; r++)
        E[hl * 8192 + (rg * 16 + rt * 32 + quad * 4 + r) * 128 + nt * 16 + l16] =
            (f16)o[rt][nt][r];
  if (l16 == 0) {
    #pragma unroll
    for (int rt = 0; rt < 2; rt++)
      #pragma unroll
      for (int r = 0; r < 4; r++)
        lpart[(size_t)(hh * 2 + ks) * 2048 + t0 + rt * 32 + quad * 4 + r] = lr[rt][r];
  }
  __syncthreads();
  const int hlT = tid >> 7;          // 0..1
  const int lt  = tid & 127;
  const int c8  = (lt & 15) * 8;
  #pragma unroll
  for (int p = 0; p < 8; p++) {
    int row = p * 8 + (lt >> 4);     // 0..63
    size_t g = ((size_t)((h * 2 + hlT) * 2 + ks) * 2048 + qb * 64 + row) * 128 + c8;
    *(uint4*)(opart + g) = *(const uint4*)(E + hlT * 8192 + row * 128 + c8);
  }
}

// =====================================================================
// Combine: merge K-halves, head-pair diff + lambda + RMS-norm -> attn f16.
// =====================================================================
__global__ __launch_bounds__(256) void combine_kernel(
    const f16* __restrict__ opart, const float* __restrict__ lpart,
    const float* __restrict__ lq1, const float* __restrict__ lk1,
    const float* __restrict__ lq2, const float* __restrict__ lk2,
    f16* __restrict__ attn)
{
  const int t   = blockIdx.x;
  const int tid = threadIdx.x;
  const int lane = tid & 63;
  const int hp  = tid >> 5;          // 0..7
  const int g   = tid & 31;
  const int c0  = g * 4;

  float a1 = lq1[lane] * lk1[lane];
  float a2 = lq2[lane] * lk2[lane];
  #pragma unroll
  for (int off = 1; off < 64; off <<= 1) {
    a1 += __shfl_xor(a1, off, 64);
    a2 += __shfl_xor(a2, off, 64);
  }
  const float lam = __expf(a1) - __expf(a2) + LAMBDA_INIT;

  const size_t TS = (size_t)2048 * 128;
  const int i00 = (hp * 2 + 0) * 2, i01 = i00 + 1;
  const int i10 = (hp * 2 + 1) * 2, i11 = i10 + 1;
  const size_t off = (size_t)t * 128 + c0;
  f16x4 v00 = *(const f16x4*)(opart + i00 * TS + off);
  f16x4 v01 = *(const f16x4*)(opart + i01 * TS + off);
  f16x4 v10 = *(const f16x4*)(opart + i10 * TS + off);
  f16x4 v11 = *(const f16x4*)(opart + i11 * TS + off);
  float l00 = lpart[i00 * 2048 + t], l01 = lpart[i01 * 2048 + t];
  float l10 = lpart[i10 * 2048 + t], l11 = lpart[i11 * 2048 + t];
  float inv0 = 1.0f / (l00 + l01), inv1 = 1.0f / (l10 + l11);
  float w00 = l00 * inv0, w01 = l01 * inv0;
  float w10 = l10 * inv1, w11 = l11 * inv1;

  float d[4], ss = 0.f;
  #pragma unroll
  for (int j = 0; j < 4; j++) {
    float o0 = w00 * (float)v00[j] + w01 * (float)v01[j];
    float o1 = w10 * (float)v10[j] + w11 * (float)v11[j];
    d[j] = o0 - lam * o1;
    ss += d[j] * d[j];
  }
  ss += __shfl_xor(ss, 1, 64);
  ss += __shfl_xor(ss, 2, 64);
  ss += __shfl_xor(ss, 4, 64);
  ss += __shfl_xor(ss, 8, 64);
  ss += __shfl_xor(ss, 16, 64);
  float rms = rsqrtf(ss * (1.0f / 128.0f) + 1e-5f) * (1.0f - LAMBDA_INIT);

  f16x4 ov;
  #pragma unroll
  for (int j = 0; j < 4; j++) ov[j] = (f16)(d[j] * rms);
  *(f16x4*)(attn + (size_t)t * 1024 + hp * 128 + c0) = ov;
}

// =====================================================================
extern "C" void kernel_launch(void* const* d_in, const int* in_sizes, int n_in,
                              void* d_out, int out_size, void* d_ws, size_t ws_size,
                              hipStream_t stream)
{
  (void)in_sizes; (void)n_in; (void)out_size; (void)ws_size;
  const float* x   = (const float*)d_in[0];
  const float* Wq  = (const float*)d_in[1];
  const float* Wk  = (const float*)d_in[2];
  const float* Wv  = (const float*)d_in[3];
  const float* Wo  = (const float*)d_in[4];
  const float* lq1 = (const float*)d_in[5];
  const float* lk1 = (const float*)d_in[6];
  const float* lq2 = (const float*)d_in[7];
  const float* lk2 = (const float*)d_in[8];
  float* out = (float*)d_out;

  const size_t TM = (size_t)T_SEQ * EMB;  // 2M elems
  const size_t WM = (size_t)EMB * EMB;    // 1M elems
  bf16*  vtws  = (bf16*)d_ws;           // 4MB
  f16*   aws   = (f16*)(vtws + TM);     // 4MB
  f16*   xf    = aws  + TM;             // 4MB
  f16*   wqf   = xf   + TM;             // 2MB each
  f16*   wkf   = wqf  + WM;
  f16*   wvf   = wkf  + WM;
  f16*   wof   = wvf  + WM;
  f16*   qf    = wof  + WM;             // 4MB
  f16*   kf    = qf   + TM;             // 4MB
  f16*   opart = kf   + TM;             // 32 tiles x 2048 x 128 f16 = 16MB
  float* lpart = (float*)(opart + (size_t)32 * 2048 * 128);  // 256KB

  convert_kernel<<<6144, 256, 0, stream>>>(x, Wq, Wk, Wv, Wo,
                                           xf, wqf, wkf, wvf, wof);
  qkv_gemm<<<768, 256, 0, stream>>>(xf, wqf, wkf, wvf, qf, kf, vtws);
  diff_attn<<<512, 256, 0, stream>>>(qf, kf, vtws, opart, lpart);
  combine_kernel<<<2048, 256, 0, stream>>>(opart, lpart, lq1, lk1, lq2, lk2, aws);
  out_gemm<<<256, 256, 0, stream>>>(aws, wof, out);
}

// Round 11
// 181.750 us; speedup vs baseline: 1.1729x; 1.1729x over previous
//
#include <hip/hip_runtime.h>
#include <hip/hip_bf16.h>

typedef __hip_bfloat16 bf16;
typedef _Float16 f16;
typedef __attribute__((ext_vector_type(8))) __bf16 bf16x8;
typedef __attribute__((ext_vector_type(8))) _Float16 f16x8;
typedef __attribute__((ext_vector_type(4))) _Float16 f16x4;
typedef __attribute__((ext_vector_type(4))) float floatx4;

#define T_SEQ 2048
#define EMB   1024
#define LAMBDA_INIT 0.35550906759096926f

// round-to-nearest-even fp32 -> bf16
__device__ __forceinline__ bf16 f2bf(float f) {
  unsigned u;
  __builtin_memcpy(&u, &f, 4);
  u += 0x7FFF + ((u >> 16) & 1);
  unsigned short h = (unsigned short)(u >> 16);
  bf16 r;
  __builtin_memcpy(&r, &h, 2);
  return r;
}

__device__ __forceinline__ void gl_lds16(const void* g, void* l) {
  __builtin_amdgcn_global_load_lds((const __attribute__((address_space(1))) void*)g,
                                   (__attribute__((address_space(3))) void*)l, 16, 0, 0);
}

__device__ __forceinline__ floatx4 mfma_bf(bf16x8 a, bf16x8 b, floatx4 c) {
  return __builtin_amdgcn_mfma_f32_16x16x32_bf16(a, b, c, 0, 0, 0);
}
__device__ __forceinline__ floatx4 mfma_h(f16x8 a, f16x8 b, floatx4 c) {
  return __builtin_amdgcn_mfma_f32_16x16x32_f16(a, b, c, 0, 0, 0);
}

// =====================================================================
// fp32 -> fp16 conversion for x, Wq, Wk, Wv, Wo.
// =====================================================================
__global__ __launch_bounds__(256) void convert_kernel(
    const float* __restrict__ x,  const float* __restrict__ wq,
    const float* __restrict__ wk, const float* __restrict__ wv,
    const float* __restrict__ wo,
    f16* __restrict__ xf, f16* __restrict__ wqf, f16* __restrict__ wkf,
    f16* __restrict__ wvf, f16* __restrict__ wof)
{
  int b = blockIdx.x;
  const float* src; f16* dst; long off;
  if      (b < 2048) { src = x;  dst = xf;  off = (long)b * 1024; }
  else if (b < 3072) { src = wq; dst = wqf; off = (long)(b - 2048) * 1024; }
  else if (b < 4096) { src = wk; dst = wkf; off = (long)(b - 3072) * 1024; }
  else if (b < 5120) { src = wv; dst = wvf; off = (long)(b - 4096) * 1024; }
  else               { src = wo; dst = wof; off = (long)(b - 5120) * 1024; }
  long i = off + threadIdx.x * 4;
  float4 v = *(const float4*)(src + i);
  f16x4 o;
  o.x = (f16)v.x; o.y = (f16)v.y; o.z = (f16)v.z; o.w = (f16)v.w;
  *(f16x4*)(dst + i) = o;
}

// =====================================================================
// fp16 NT GEMM, 64x128 tile, BK=64, 24KB LDS staging.
// MODE 2 = RoPE-Q epilogue (fold 0.125) -> fp16; MODE 3 = RoPE-K (inv scale)
// MODE 0 = bf16 out (V);  MODE 1 = fp32 out (output projection)
// =====================================================================
template <int MODE>
__device__ __forceinline__ void gemm64x128_f16(
    const f16* __restrict__ A_, const f16* __restrict__ B_,
    void* C0v, int K, int ldc, int m0, int n0, char* smem)
{
  f16* As = (f16*)smem;              // 64 x 64 swz (8 KB)
  f16* Bs = (f16*)(smem + 8192);     // 128 x 64 swz (16 KB)
  const int tid  = threadIdx.x;
  const int wave = tid >> 6, lane = tid & 63, quad = lane >> 4, l16 = lane & 15;
  const int mo = (wave & 1) << 5;
  const int no = (wave >> 1) << 6;

  floatx4 acc[2][4];
  #pragma unroll
  for (int i = 0; i < 2; i++)
    #pragma unroll
    for (int j = 0; j < 4; j++) { acc[i][j][0]=0.f; acc[i][j][1]=0.f; acc[i][j][2]=0.f; acc[i][j][3]=0.f; }

  const int srow = tid >> 3;
  const int ch   = (tid & 7) ^ (srow & 7);
  const long aoff = (long)(m0 + srow) * K + ch * 8;
  const long boff = (long)(n0 + srow) * K + ch * 8;
  const int wb = wave << 10;

  for (int k0 = 0; k0 < K; k0 += 64) {
    #pragma unroll
    for (int rr = 0; rr < 2; rr++)
      gl_lds16(A_ + aoff + k0 + (long)rr * 32 * K, smem + wb + rr * 4096);
    #pragma unroll
    for (int rr = 0; rr < 4; rr++)
      gl_lds16(B_ + boff + k0 + (long)rr * 32 * K, smem + 8192 + wb + rr * 4096);
    __syncthreads();
    #pragma unroll
    for (int kt = 0; kt < 2; kt++) {
      f16x8 a[2], b[4];
      #pragma unroll
      for (int i = 0; i < 2; i++) {
        int m = mo + i * 16 + l16;
        a[i] = *(const f16x8*)(As + m * 64 + ((((kt << 2) | quad) ^ (m & 7)) << 3));
      }
      #pragma unroll
      for (int j = 0; j < 4; j++) {
        int n = no + j * 16 + l16;
        b[j] = *(const f16x8*)(Bs + n * 64 + ((((kt << 2) | quad) ^ (n & 7)) << 3));
      }
      #pragma unroll
      for (int i = 0; i < 2; i++)
        #pragma unroll
        for (int j = 0; j < 4; j++)
          acc[i][j] = mfma_h(a[i], b[j], acc[i][j]);
    }
    __syncthreads();
  }

  if (MODE == 1) {
    #pragma unroll
    for (int i = 0; i < 2; i++)
      #pragma unroll
      for (int j = 0; j < 4; j++)
        #pragma unroll
        for (int r = 0; r < 4; r++) {
          int row = m0 + mo + i * 16 + quad * 4 + r;
          int col = n0 + no + j * 16 + l16;
          ((float*)C0v)[(long)row * ldc + col] = acc[i][j][r];
        }
  } else {
    unsigned short* E = (unsigned short*)smem;   // 64x128 2-byte = 16 KB
    #pragma unroll
    for (int i = 0; i < 2; i++)
      #pragma unroll
      for (int j = 0; j < 4; j++)
        #pragma unroll
        for (int r = 0; r < 4; r++) {
          int row = mo + i * 16 + quad * 4 + r;
          int col = no + j * 16 + l16;
          float v = acc[i][j][r];
          unsigned short bits;
          if (MODE == 0) {
            bf16 t = f2bf(v);
            __builtin_memcpy(&bits, &t, 2);
          } else {
            float p = __shfl_xor(v, 1, 64);
            int d = col & 63;
            float fr = (float)(m0 + row) * __expf((float)(d >> 1) * -0.28782313662425574f);
            float sn, cs;
            sincosf(fr, &sn, &cs);
            float rot = (col & 1) ? fmaf(v, cs, p * sn) : fmaf(v, cs, -p * sn);
            float power = (float)(m0 + row - 1024) * (1.0f / 512.0f);
            if (MODE == 3) power = -power;
            float sv = fmaf(2.0f, (float)(d & 31), 25.6f) * (1.0f / 89.6f);
            float s = __expf(power * __logf(sv));
            float ov = rot * s;
            if (MODE == 2) ov *= 0.125f;
            f16 t = (f16)ov;
            __builtin_memcpy(&bits, &t, 2);
          }
          E[row * 128 + col] = bits;
        }
    __syncthreads();
    const int rr0 = tid >> 4;
    const int c8  = (tid & 15) * 8;
    #pragma unroll
    for (int p2 = 0; p2 < 4; p2++) {
      int row = p2 * 16 + rr0;
      *(uint4*)((unsigned short*)C0v + (long)(m0 + row) * ldc + n0 + c8) =
          *(const uint4*)(E + row * 128 + c8);
    }
  }
}

__global__ __launch_bounds__(256) void qkv_gemm(
    const f16* __restrict__ xf,
    const f16* __restrict__ wqf, const f16* __restrict__ wkf,
    const f16* __restrict__ wvf,
    f16* __restrict__ qf, f16* __restrict__ kf, bf16* __restrict__ vt)
{
  __shared__ char smem[24576];
  int bid = blockIdx.x;
  if (bid < 256) {
    gemm64x128_f16<2>(xf, wqf, qf, 1024, 1024, (bid >> 3) * 64, (bid & 7) * 128, smem);
  } else if (bid < 512) {
    bid -= 256;
    gemm64x128_f16<3>(xf, wkf, kf, 1024, 1024, (bid >> 3) * 64, (bid & 7) * 128, smem);
  } else {
    bid -= 512;
    gemm64x128_f16<0>(wvf, xf, vt, 1024, 2048, (bid >> 4) * 64, (bid & 15) * 128, smem);
  }
}

__global__ __launch_bounds__(256) void out_gemm(const f16* __restrict__ attn,
                                                const f16* __restrict__ Wo,
                                                float* __restrict__ out)
{
  __shared__ char smem[24576];
  gemm64x128_f16<1>(attn, Wo, out, 1024, 1024,
                    (blockIdx.x >> 3) * 64, (blockIdx.x & 7) * 128, smem);
}

// =====================================================================
// Differential flash attention (R8 structure: 32 q-rows/block, full K range,
// grid 512, LDS 40KB, VGPR ~64) with XCD-affinity block swizzle:
// hp = blockIdx & 7  →  under round-robin block→XCD dispatch, all blocks of
// one head pair land on one XCD, so its K/V (~1MB) stays L2-resident and the
// pre-barrier vmcnt drain waits on L2 (~200cyc) instead of HBM (~900cyc).
// =====================================================================
__global__ __launch_bounds__(256) void diff_attn(
    const f16* __restrict__ qf_, const f16* __restrict__ kf_,
    const bf16* __restrict__ vt,
    const float* __restrict__ lq1, const float* __restrict__ lk1,
    const float* __restrict__ lq2, const float* __restrict__ lk2,
    f16* __restrict__ attn)
{
  __shared__ char smem[40960];
  // K0 @0 (8KB) | K1 @8192 (8KB) | V @16384 (16KB) | P @32768 (8KB)
  bf16* Vs = (bf16*)(smem + 16384);
  float* Cb = (float*)smem;              // 32x128 f32 (16KB), reused after loop

  const int tid  = threadIdx.x;
  const int wave = tid >> 6, lane = tid & 63, quad = lane >> 4, l16 = lane & 15;
  const int h  = blockIdx.x & 7;         // head pair — XCD-affine under %8 dispatch
  const int qb = blockIdx.x >> 3;        // q block 0..63
  const int hl = wave >> 1;              // 0: head 2h, 1: head 2h+1
  const int rg = wave & 1;
  const int hh = h * 2 + hl;
  const int t0 = qb * 32 + rg * 16;

  float a1 = lq1[lane] * lk1[lane];
  float a2 = lq2[lane] * lk2[lane];
  #pragma unroll
  for (int off = 1; off < 64; off <<= 1) {
    a1 += __shfl_xor(a1, off, 64);
    a2 += __shfl_xor(a2, off, 64);
  }
  const float lam = __expf(a1) - __expf(a2) + LAMBDA_INIT;

  f16x8 qfr[2];
  {
    const f16* qrow = qf_ + (long)(t0 + l16) * EMB + hh * 64;
    qfr[0] = *(const f16x8*)(qrow + quad * 8);
    qfr[1] = *(const f16x8*)(qrow + 32 + quad * 8);
  }

  floatx4 o[8];
  #pragma unroll
  for (int i = 0; i < 8; i++) { o[i][0]=0.f; o[i][1]=0.f; o[i][2]=0.f; o[i][3]=0.f; }
  float lr[4] = {0.f, 0.f, 0.f, 0.f};

  const int srow = lane >> 3;
  const int ch   = (lane & 7) ^ srow;
  const f16*  kgp = kf_ + (long)(h * 2 + (wave & 1)) * 64 + (long)srow * EMB + ch * 8;
  const bf16* vgp = vt + (long)(h * 128 + (wave - 2) * 64 + srow) * T_SEQ + ch * 8;
  char* ldstK = smem + wave * 8192;
  char* ldstV = smem + 16384 + (wave - 2) * 8192;

  for (int kb = 0; kb < T_SEQ; kb += 64) {
    if (wave < 2) {
      #pragma unroll
      for (int j = 0; j < 8; j++)
        gl_lds16(kgp + (long)kb * EMB + (long)j * 8 * EMB, ldstK + j * 1024);
    } else {
      #pragma unroll
      for (int j = 0; j < 8; j++)
        gl_lds16(vgp + kb + (long)j * 8 * T_SEQ, ldstV + j * 1024);
    }
    __syncthreads();

    const f16* Ks = (const f16*)(smem + hl * 8192);
    floatx4 s4[4];
    #pragma unroll
    for (int nt = 0; nt < 4; nt++) {
      s4[nt][0]=0.f; s4[nt][1]=0.f; s4[nt][2]=0.f; s4[nt][3]=0.f;
      #pragma unroll
      for (int kt = 0; kt < 2; kt++) {
        int n = nt * 16 + l16;
        f16x8 kfr = *(const f16x8*)(Ks + n * 64 + ((((kt << 2) | quad) ^ (n & 7)) << 3));
        s4[nt] = mfma_h(qfr[kt], kfr, s4[nt]);
      }
    }
    // static-offset softmax: P = exp2(s*log2e - 12*log2e)
    #pragma unroll
    for (int nt = 0; nt < 4; nt++)
      #pragma unroll
      for (int r = 0; r < 4; r++) {
        float pv = __builtin_amdgcn_exp2f(
            fmaf(s4[nt][r], 1.4426950408889634f, -17.312340490667562f));
        s4[nt][r] = pv;
        lr[r] += pv;
      }

    // P (C-layout) -> LDS (swizzled) -> A-layout fragments (bf16)
    bf16* Pw = (bf16*)(smem + 32768) + wave * 1024;
    #pragma unroll
    for (int nt = 0; nt < 4; nt++) {
      int col = nt * 16 + l16;
      #pragma unroll
      for (int r = 0; r < 4; r++) {
        int row = quad * 4 + r;
        Pw[row * 64 + (((col >> 3) ^ (row & 7)) << 3) + (col & 7)] = f2bf(s4[nt][r]);
      }
    }
    __asm__ volatile("s_waitcnt lgkmcnt(0)" ::: "memory");
    bf16x8 pf[2];
    #pragma unroll
    for (int kt = 0; kt < 2; kt++)
      pf[kt] = *(const bf16x8*)(Pw + l16 * 64 + ((((kt << 2) | quad) ^ (l16 & 7)) << 3));

    #pragma unroll
    for (int nt = 0; nt < 8; nt++) {
      #pragma unroll
      for (int kt = 0; kt < 2; kt++) {
        int c = nt * 16 + l16;
        bf16x8 vf = *(const bf16x8*)(Vs + c * 64 + ((((kt << 2) | quad) ^ (c & 7)) << 3));
        o[nt] = mfma_bf(pf[kt], vf, o[nt]);
      }
    }
    __syncthreads();
  }

  #pragma unroll
  for (int r = 0; r < 4; r++) {
    lr[r] += __shfl_xor(lr[r], 1, 64);
    lr[r] += __shfl_xor(lr[r], 2, 64);
    lr[r] += __shfl_xor(lr[r], 4, 64);
    lr[r] += __shfl_xor(lr[r], 8, 64);
  }
  #pragma unroll
  for (int nt = 0; nt < 8; nt++)
    #pragma unroll
    for (int r = 0; r < 4; r++) o[nt][r] /= lr[r];

  if (hl == 1) {
    #pragma unroll
    for (int nt = 0; nt < 8; nt++)
      #pragma unroll
      for (int r = 0; r < 4; r++)
        Cb[(rg * 16 + quad * 4 + r) * 128 + nt * 16 + l16] = o[nt][r];
  }
  __syncthreads();
  if (hl == 0) {
    float d[8][4];
    float ss[4] = {0.f, 0.f, 0.f, 0.f};
    #pragma unroll
    for (int nt = 0; nt < 8; nt++)
      #pragma unroll
      for (int r = 0; r < 4; r++) {
        float v = o[nt][r] - lam * Cb[(rg * 16 + quad * 4 + r) * 128 + nt * 16 + l16];
        d[nt][r] = v;
        ss[r] += v * v;
      }
    #pragma unroll
    for (int r = 0; r < 4; r++) {
      ss[r] += __shfl_xor(ss[r], 1, 64);
      ss[r] += __shfl_xor(ss[r], 2, 64);
      ss[r] += __shfl_xor(ss[r], 4, 64);
      ss[r] += __shfl_xor(ss[r], 8, 64);
      ss[r] = rsqrtf(ss[r] * (1.0f / 128.0f) + 1e-5f) * (1.0f - LAMBDA_INIT);
    }
    #pragma unroll
    for (int nt = 0; nt < 8; nt++)
      #pragma unroll
      for (int r = 0; r < 4; r++)
        attn[(long)(t0 + quad * 4 + r) * EMB + h * 128 + nt * 16 + l16] =
            (f16)(d[nt][r] * ss[r]);
  }
}

// =====================================================================
extern "C" void kernel_launch(void* const* d_in, const int* in_sizes, int n_in,
                              void* d_out, int out_size, void* d_ws, size_t ws_size,
                              hipStream_t stream)
{
  (void)in_sizes; (void)n_in; (void)out_size; (void)ws_size;
  const float* x   = (const float*)d_in[0];
  const float* Wq  = (const float*)d_in[1];
  const float* Wk  = (const float*)d_in[2];
  const float* Wv  = (const float*)d_in[3];
  const float* Wo  = (const float*)d_in[4];
  const float* lq1 = (const float*)d_in[5];
  const float* lk1 = (const float*)d_in[6];
  const float* lq2 = (const float*)d_in[7];
  const float* lk2 = (const float*)d_in[8];
  float* out = (float*)d_out;

  const size_t TM = (size_t)T_SEQ * EMB;  // 2M elems
  const size_t WM = (size_t)EMB * EMB;    // 1M elems
  bf16* vtws = (bf16*)d_ws;          // 4MB
  f16*  aws  = (f16*)(vtws + TM);    // 4MB
  f16*  xf   = aws  + TM;            // 4MB
  f16*  wqf  = xf   + TM;            // 2MB
  f16*  wkf  = wqf  + WM;
  f16*  wvf  = wkf  + WM;
  f16*  wof  = wvf  + WM;
  f16*  qf   = wof  + WM;            // 4MB
  f16*  kf   = qf   + TM;            // 4MB

  convert_kernel<<<6144, 256, 0, stream>>>(x, Wq, Wk, Wv, Wo,
                                           xf, wqf, wkf, wvf, wof);
  qkv_gemm<<<768, 256, 0, stream>>>(xf, wqf, wkf, wvf, qf, kf, vtws);
  diff_attn<<<512, 256, 0, stream>>>(qf, kf, vtws, lq1, lk1, lq2, lk2, aws);
  out_gemm<<<256, 256, 0, stream>>>(aws, wof, out);
}

// Round 12
// 179.525 us; speedup vs baseline: 1.1875x; 1.0124x over previous
//
#include <hip/hip_runtime.h>
#include <hip/hip_bf16.h>

typedef __hip_bfloat16 bf16;
typedef _Float16 f16;
typedef __attribute__((ext_vector_type(8))) __bf16 bf16x8;
typedef __attribute__((ext_vector_type(8))) _Float16 f16x8;
typedef __attribute__((ext_vector_type(4))) _Float16 f16x4;
typedef __attribute__((ext_vector_type(4))) float floatx4;
typedef __attribute__((ext_vector_type(16))) float floatx16;

#define T_SEQ 2048
#define EMB   1024
#define LAMBDA_INIT 0.35550906759096926f

// round-to-nearest-even fp32 -> bf16
__device__ __forceinline__ bf16 f2bf(float f) {
  unsigned u;
  __builtin_memcpy(&u, &f, 4);
  u += 0x7FFF + ((u >> 16) & 1);
  unsigned short h = (unsigned short)(u >> 16);
  bf16 r;
  __builtin_memcpy(&r, &h, 2);
  return r;
}

__device__ __forceinline__ void gl_lds16(const void* g, void* l) {
  __builtin_amdgcn_global_load_lds((const __attribute__((address_space(1))) void*)g,
                                   (__attribute__((address_space(3))) void*)l, 16, 0, 0);
}

__device__ __forceinline__ floatx4 mfma_h(f16x8 a, f16x8 b, floatx4 c) {
  return __builtin_amdgcn_mfma_f32_16x16x32_f16(a, b, c, 0, 0, 0);
}
__device__ __forceinline__ floatx16 mfma32_h(f16x8 a, f16x8 b, floatx16 c) {
  return __builtin_amdgcn_mfma_f32_32x32x16_f16(a, b, c, 0, 0, 0);
}
__device__ __forceinline__ floatx16 mfma32_bf(bf16x8 a, bf16x8 b, floatx16 c) {
  return __builtin_amdgcn_mfma_f32_32x32x16_bf16(a, b, c, 0, 0, 0);
}

// =====================================================================
// fp32 -> fp16 conversion for x, Wq, Wk, Wv, Wo.
// =====================================================================
__global__ __launch_bounds__(256) void convert_kernel(
    const float* __restrict__ x,  const float* __restrict__ wq,
    const float* __restrict__ wk, const float* __restrict__ wv,
    const float* __restrict__ wo,
    f16* __restrict__ xf, f16* __restrict__ wqf, f16* __restrict__ wkf,
    f16* __restrict__ wvf, f16* __restrict__ wof)
{
  int b = blockIdx.x;
  const float* src; f16* dst; long off;
  if      (b < 2048) { src = x;  dst = xf;  off = (long)b * 1024; }
  else if (b < 3072) { src = wq; dst = wqf; off = (long)(b - 2048) * 1024; }
  else if (b < 4096) { src = wk; dst = wkf; off = (long)(b - 3072) * 1024; }
  else if (b < 5120) { src = wv; dst = wvf; off = (long)(b - 4096) * 1024; }
  else               { src = wo; dst = wof; off = (long)(b - 5120) * 1024; }
  long i = off + threadIdx.x * 4;
  float4 v = *(const float4*)(src + i);
  f16x4 o;
  o.x = (f16)v.x; o.y = (f16)v.y; o.z = (f16)v.z; o.w = (f16)v.w;
  *(f16x4*)(dst + i) = o;
}

// =====================================================================
// fp16 NT GEMM, 64x128 tile, BK=64, 24KB LDS staging.
// MODE 2 = RoPE-Q epilogue (fold 0.125) -> fp16; MODE 3 = RoPE-K (inv scale)
// MODE 0 = bf16 out (V);  MODE 1 = fp32 out (output projection)
// =====================================================================
template <int MODE>
__device__ __forceinline__ void gemm64x128_f16(
    const f16* __restrict__ A_, const f16* __restrict__ B_,
    void* C0v, int K, int ldc, int m0, int n0, char* smem)
{
  f16* As = (f16*)smem;              // 64 x 64 swz (8 KB)
  f16* Bs = (f16*)(smem + 8192);     // 128 x 64 swz (16 KB)
  const int tid  = threadIdx.x;
  const int wave = tid >> 6, lane = tid & 63, quad = lane >> 4, l16 = lane & 15;
  const int mo = (wave & 1) << 5;
  const int no = (wave >> 1) << 6;

  floatx4 acc[2][4];
  #pragma unroll
  for (int i = 0; i < 2; i++)
    #pragma unroll
    for (int j = 0; j < 4; j++) { acc[i][j][0]=0.f; acc[i][j][1]=0.f; acc[i][j][2]=0.f; acc[i][j][3]=0.f; }

  const int srow = tid >> 3;
  const int ch   = (tid & 7) ^ (srow & 7);
  const long aoff = (long)(m0 + srow) * K + ch * 8;
  const long boff = (long)(n0 + srow) * K + ch * 8;
  const int wb = wave << 10;

  for (int k0 = 0; k0 < K; k0 += 64) {
    #pragma unroll
    for (int rr = 0; rr < 2; rr++)
      gl_lds16(A_ + aoff + k0 + (long)rr * 32 * K, smem + wb + rr * 4096);
    #pragma unroll
    for (int rr = 0; rr < 4; rr++)
      gl_lds16(B_ + boff + k0 + (long)rr * 32 * K, smem + 8192 + wb + rr * 4096);
    __syncthreads();
    #pragma unroll
    for (int kt = 0; kt < 2; kt++) {
      f16x8 a[2], b[4];
      #pragma unroll
      for (int i = 0; i < 2; i++) {
        int m = mo + i * 16 + l16;
        a[i] = *(const f16x8*)(As + m * 64 + ((((kt << 2) | quad) ^ (m & 7)) << 3));
      }
      #pragma unroll
      for (int j = 0; j < 4; j++) {
        int n = no + j * 16 + l16;
        b[j] = *(const f16x8*)(Bs + n * 64 + ((((kt << 2) | quad) ^ (n & 7)) << 3));
      }
      #pragma unroll
      for (int i = 0; i < 2; i++)
        #pragma unroll
        for (int j = 0; j < 4; j++)
          acc[i][j] = mfma_h(a[i], b[j], acc[i][j]);
    }
    __syncthreads();
  }

  if (MODE == 1) {
    #pragma unroll
    for (int i = 0; i < 2; i++)
      #pragma unroll
      for (int j = 0; j < 4; j++)
        #pragma unroll
        for (int r = 0; r < 4; r++) {
          int row = m0 + mo + i * 16 + quad * 4 + r;
          int col = n0 + no + j * 16 + l16;
          ((float*)C0v)[(long)row * ldc + col] = acc[i][j][r];
        }
  } else {
    unsigned short* E = (unsigned short*)smem;   // 64x128 2-byte = 16 KB
    #pragma unroll
    for (int i = 0; i < 2; i++)
      #pragma unroll
      for (int j = 0; j < 4; j++)
        #pragma unroll
        for (int r = 0; r < 4; r++) {
          int row = mo + i * 16 + quad * 4 + r;
          int col = no + j * 16 + l16;
          float v = acc[i][j][r];
          unsigned short bits;
          if (MODE == 0) {
            bf16 t = f2bf(v);
            __builtin_memcpy(&bits, &t, 2);
          } else {
            float p = __shfl_xor(v, 1, 64);
            int d = col & 63;
            float fr = (float)(m0 + row) * __expf((float)(d >> 1) * -0.28782313662425574f);
            float sn, cs;
            sincosf(fr, &sn, &cs);
            float rot = (col & 1) ? fmaf(v, cs, p * sn) : fmaf(v, cs, -p * sn);
            float power = (float)(m0 + row - 1024) * (1.0f / 512.0f);
            if (MODE == 3) power = -power;
            float sv = fmaf(2.0f, (float)(d & 31), 25.6f) * (1.0f / 89.6f);
            float s = __expf(power * __logf(sv));
            float ov = rot * s;
            if (MODE == 2) ov *= 0.125f;
            f16 t = (f16)ov;
            __builtin_memcpy(&bits, &t, 2);
          }
          E[row * 128 + col] = bits;
        }
    __syncthreads();
    const int rr0 = tid >> 4;
    const int c8  = (tid & 15) * 8;
    #pragma unroll
    for (int p2 = 0; p2 < 4; p2++) {
      int row = p2 * 16 + rr0;
      *(uint4*)((unsigned short*)C0v + (long)(m0 + row) * ldc + n0 + c8) =
          *(const uint4*)(E + row * 128 + c8);
    }
  }
}

__global__ __launch_bounds__(256) void qkv_gemm(
    const f16* __restrict__ xf,
    const f16* __restrict__ wqf, const f16* __restrict__ wkf,
    const f16* __restrict__ wvf,
    f16* __restrict__ qf, f16* __restrict__ kf, bf16* __restrict__ vt)
{
  __shared__ char smem[24576];
  int bid = blockIdx.x;
  if (bid < 256) {
    gemm64x128_f16<2>(xf, wqf, qf, 1024, 1024, (bid >> 3) * 64, (bid & 7) * 128, smem);
  } else if (bid < 512) {
    bid -= 256;
    gemm64x128_f16<3>(xf, wkf, kf, 1024, 1024, (bid >> 3) * 64, (bid & 7) * 128, smem);
  } else {
    bid -= 512;
    gemm64x128_f16<0>(wvf, xf, vt, 1024, 2048, (bid >> 4) * 64, (bid & 15) * 128, smem);
  }
}

__global__ __launch_bounds__(256) void out_gemm(const f16* __restrict__ attn,
                                                const f16* __restrict__ Wo,
                                                float* __restrict__ out)
{
  __shared__ char smem[24576];
  gemm64x128_f16<1>(attn, Wo, out, 1024, 1024,
                    (blockIdx.x >> 3) * 64, (blockIdx.x & 7) * 128, smem);
}

// =====================================================================
// Differential flash attention, 32x32x16 MFMA edition.
// Wave w = (head hl = w>>1, key-half ws = w&1). Each wave:
//   QK: S[32 rows][32 keys of its half] — 4 MFMAs, 4 K-frag reads (Q in regs)
//   PV: O[32 rows][128] over its own 32 keys — 8 MFMAs, 8 V + 2 P reads.
// P is wave-private (lgkmcnt-only transpose, no extra barrier). Key-half
// O / denominator partials merged once in the epilogue via LDS.
// 32x32x16 reads give 8 MAC/byte vs 4 for 16x16x32 → LDS reads/wave-iter
// drop 26 → 14. A: m=lane&31, k=(lane>>5)*8+j; B mirrors; C/D: col=lane&31,
// row=(reg&3)+8*(reg>>2)+4*(lane>>5) [HW-verified m74/m101].
// XCD swizzle retained (h = blockIdx & 7).
// =====================================================================
__global__ __launch_bounds__(256) void diff_attn(
    const f16* __restrict__ qf_, const f16* __restrict__ kf_,
    const bf16* __restrict__ vt,
    const float* __restrict__ lq1, const float* __restrict__ lk1,
    const float* __restrict__ lq2, const float* __restrict__ lk2,
    f16* __restrict__ attn)
{
  __shared__ char smem[40960];
  // K0 @0 (8KB) | K1 @8192 (8KB) | V @16384 (16KB) | P @32768 (4 waves x 2KB)
  bf16* Vs = (bf16*)(smem + 16384);

  const int tid  = threadIdx.x;
  const int wave = tid >> 6, lane = tid & 63;
  const int l32 = lane & 31, lh = lane >> 5;
  const int h  = blockIdx.x & 7;         // head pair — XCD-affine
  const int qb = blockIdx.x >> 3;        // q block 0..63 (32 rows each)
  const int hl = wave >> 1;              // head in pair
  const int ws = wave & 1;               // key-half of this wave
  const int hh = h * 2 + hl;
  const int t0 = qb * 32;

  float a1 = lq1[lane] * lk1[lane];
  float a2 = lq2[lane] * lk2[lane];
  #pragma unroll
  for (int off = 1; off < 64; off <<= 1) {
    a1 += __shfl_xor(a1, off, 64);
    a2 += __shfl_xor(a2, off, 64);
  }
  const float lam = __expf(a1) - __expf(a2) + LAMBDA_INIT;

  // Q A-frags (32 rows x 64 d): k = kt*16 + lh*8 + j
  f16x8 qfr[4];
  {
    const f16* qrow = qf_ + (long)(t0 + l32) * EMB + hh * 64 + lh * 8;
    #pragma unroll
    for (int kt = 0; kt < 4; kt++) qfr[kt] = *(const f16x8*)(qrow + kt * 16);
  }

  floatx16 o[4];   // nt over Dv=128, un-normalized accumulation
  #pragma unroll
  for (int nt = 0; nt < 4; nt++)
    #pragma unroll
    for (int r = 0; r < 16; r++) o[nt][r] = 0.f;
  float lr[16];
  #pragma unroll
  for (int r = 0; r < 16; r++) lr[r] = 0.f;

  // staging (unchanged): waves 0,1 -> K0,K1; waves 2,3 -> V halves
  const int srow = lane >> 3;
  const int ch   = (lane & 7) ^ srow;
  const f16*  kgp = kf_ + (long)(h * 2 + (wave & 1)) * 64 + (long)srow * EMB + ch * 8;
  const bf16* vgp = vt + (long)(h * 128 + (wave - 2) * 64 + srow) * T_SEQ + ch * 8;
  char* ldstK = smem + wave * 8192;
  char* ldstV = smem + 16384 + (wave - 2) * 8192;

  bf16* Pw = (bf16*)(smem + 32768) + wave * 1024;   // 32 rows x 32 keys (2KB)

  for (int kb = 0; kb < T_SEQ; kb += 64) {
    if (wave < 2) {
      #pragma unroll
      for (int j = 0; j < 8; j++)
        gl_lds16(kgp + (long)kb * EMB + (long)j * 8 * EMB, ldstK + j * 1024);
    } else {
      #pragma unroll
      for (int j = 0; j < 8; j++)
        gl_lds16(vgp + kb + (long)j * 8 * T_SEQ, ldstV + j * 1024);
    }
    __syncthreads();

    const f16* Ks = (const f16*)(smem + hl * 8192);
    // QK: S[32][ws*32..+32], kt over d=64
    floatx16 s;
    #pragma unroll
    for (int r = 0; r < 16; r++) s[r] = 0.f;
    #pragma unroll
    for (int kt = 0; kt < 4; kt++) {
      int krow = ws * 32 + l32;
      int c = kt * 2 + lh;
      f16x8 kfr = *(const f16x8*)(Ks + krow * 64 + ((c ^ (krow & 7)) << 3));
      s = mfma32_h(qfr[kt], kfr, s);
    }
    // static-offset softmax
    #pragma unroll
    for (int r = 0; r < 16; r++) {
      float pv = __builtin_amdgcn_exp2f(
          fmaf(s[r], 1.4426950408889634f, -17.312340490667562f));
      s[r] = pv;
      lr[r] += pv;
    }
    // P (C-layout) -> wave-private LDS (swizzled): row m, col n=l32
    #pragma unroll
    for (int r = 0; r < 16; r++) {
      int m = (r & 3) + 8 * (r >> 2) + 4 * lh;
      Pw[m * 32 + (((l32 >> 3) ^ ((m >> 1) & 3)) << 3) + (l32 & 7)] = f2bf(s[r]);
    }
    __asm__ volatile("s_waitcnt lgkmcnt(0)" ::: "memory");
    // P A-frags: m=l32, k over own 32 keys
    bf16x8 pf[2];
    #pragma unroll
    for (int kt = 0; kt < 2; kt++) {
      int c = kt * 2 + lh;
      pf[kt] = *(const bf16x8*)(Pw + l32 * 32 + ((c ^ ((l32 >> 1) & 3)) << 3));
    }
    // PV: O += P V over own keys; V key-chunk = ws*4 + kt*2 + lh
    #pragma unroll
    for (int nt = 0; nt < 4; nt++) {
      #pragma unroll
      for (int kt = 0; kt < 2; kt++) {
        int vrow = nt * 32 + l32;
        int c = ws * 4 + kt * 2 + lh;
        bf16x8 vf = *(const bf16x8*)(Vs + vrow * 64 + ((c ^ (vrow & 7)) << 3));
        o[nt] = mfma32_bf(pf[kt], vf, o[nt]);
      }
    }
    __syncthreads();
  }

  // reduce lr across the 32 lanes of each lh group (cols of each row)
  #pragma unroll
  for (int r = 0; r < 16; r++) {
    lr[r] += __shfl_xor(lr[r], 1, 64);
    lr[r] += __shfl_xor(lr[r], 2, 64);
    lr[r] += __shfl_xor(lr[r], 4, 64);
    lr[r] += __shfl_xor(lr[r], 8, 64);
    lr[r] += __shfl_xor(lr[r], 16, 64);
  }

  float* Cb = (float*)smem;                  // 2 heads x 32x128 fp32 = 32KB
  float* Lb = (float*)(smem + 32768);        // per-wave row denominators

  // phase 1: key-half ws==1 publishes raw O and lr
  if (ws == 1) {
    #pragma unroll
    for (int r = 0; r < 16; r++) {
      int m = (r & 3) + 8 * (r >> 2) + 4 * lh;
      #pragma unroll
      for (int nt = 0; nt < 4; nt++)
        Cb[hl * 4096 + m * 128 + nt * 32 + l32] = o[nt][r];
      if (l32 == 0) Lb[hl * 32 + m] = lr[r];
    }
  }
  __syncthreads();
  // phase 2: ws==0 merges halves and normalizes
  if (ws == 0) {
    #pragma unroll
    for (int r = 0; r < 16; r++) {
      int m = (r & 3) + 8 * (r >> 2) + 4 * lh;
      float inv = 1.0f / (lr[r] + Lb[hl * 32 + m]);
      #pragma unroll
      for (int nt = 0; nt < 4; nt++)
        o[nt][r] = (o[nt][r] + Cb[hl * 4096 + m * 128 + nt * 32 + l32]) * inv;
    }
  }
  __syncthreads();
  // phase 3: head1 publishes normalized O1
  if (hl == 1 && ws == 0) {
    #pragma unroll
    for (int r = 0; r < 16; r++) {
      int m = (r & 3) + 8 * (r >> 2) + 4 * lh;
      #pragma unroll
      for (int nt = 0; nt < 4; nt++)
        Cb[4096 + m * 128 + nt * 32 + l32] = o[nt][r];
    }
  }
  __syncthreads();
  // phase 4: head0 does diff + rms-norm + store
  if (hl == 0 && ws == 0) {
    float ss[16];
    #pragma unroll
    for (int r = 0; r < 16; r++) {
      int m = (r & 3) + 8 * (r >> 2) + 4 * lh;
      ss[r] = 0.f;
      #pragma unroll
      for (int nt = 0; nt < 4; nt++) {
        float v = o[nt][r] - lam * Cb[4096 + m * 128 + nt * 32 + l32];
        o[nt][r] = v;
        ss[r] += v * v;
      }
    }
    #pragma unroll
    for (int r = 0; r < 16; r++) {
      ss[r] += __shfl_xor(ss[r], 1, 64);
      ss[r] += __shfl_xor(ss[r], 2, 64);
      ss[r] += __shfl_xor(ss[r], 4, 64);
      ss[r] += __shfl_xor(ss[r], 8, 64);
      ss[r] += __shfl_xor(ss[r], 16, 64);
      float rms = rsqrtf(ss[r] * (1.0f / 128.0f) + 1e-5f) * (1.0f - LAMBDA_INIT);
      int m = (r & 3) + 8 * (r >> 2) + 4 * lh;
      #pragma unroll
      for (int nt = 0; nt < 4; nt++)
        attn[(long)(t0 + m) * EMB + h * 128 + nt * 32 + l32] = (f16)(o[nt][r] * rms);
    }
  }
}

// =====================================================================
extern "C" void kernel_launch(void* const* d_in, const int* in_sizes, int n_in,
                              void* d_out, int out_size, void* d_ws, size_t ws_size,
                              hipStream_t stream)
{
  (void)in_sizes; (void)n_in; (void)out_size; (void)ws_size;
  const float* x   = (const float*)d_in[0];
  const float* Wq  = (const float*)d_in[1];
  const float* Wk  = (const float*)d_in[2];
  const float* Wv  = (const float*)d_in[3];
  const float* Wo  = (const float*)d_in[4];
  const float* lq1 = (const float*)d_in[5];
  const float* lk1 = (const float*)d_in[6];
  const float* lq2 = (const float*)d_in[7];
  const float* lk2 = (const float*)d_in[8];
  float* out = (float*)d_out;

  const size_t TM = (size_t)T_SEQ * EMB;  // 2M elems
  const size_t WM = (size_t)EMB * EMB;    // 1M elems
  bf16* vtws = (bf16*)d_ws;          // 4MB
  f16*  aws  = (f16*)(vtws + TM);    // 4MB
  f16*  xf   = aws  + TM;            // 4MB
  f16*  wqf  = xf   + TM;            // 2MB
  f16*  wkf  = wqf  + WM;
  f16*  wvf  = wkf  + WM;
  f16*  wof  = wvf  + WM;
  f16*  qf   = wof  + WM;            // 4MB
  f16*  kf   = qf   + TM;            // 4MB

  convert_kernel<<<6144, 256, 0, stream>>>(x, Wq, Wk, Wv, Wo,
                                           xf, wqf, wkf, wvf, wof);
  qkv_gemm<<<768, 256, 0, stream>>>(xf, wqf, wkf, wvf, qf, kf, vtws);
  diff_attn<<<512, 256, 0, stream>>>(qf, kf, vtws, lq1, lk1, lq2, lk2, aws);
  out_gemm<<<256, 256, 0, stream>>>(aws, wof, out);
}